// Round 21
// baseline (158.033 us; speedup 1.0000x reference)
//
#include <hip/hip_runtime.h>

// FreqFusion forward, f32. Shapes fixed: B=2, C=256, CC=64, HR=128x128, LR=64x64.
// Scratch: intermediates live inside d_out; mask_hr_n uses d_ws when ws_size permits,
// enabling the merged final dispatch (hr_out + lr_out overlap).
#define HWH 16384   // 128*128
#define HWL 4096    // 64*64
#define WH 128
#define WL 64

// ---------------- hamming helpers ----------------
__device__ __forceinline__ float ham3v(int t) {
    const float h[3] = {0.08f, 1.0f, 0.08f};
    return h[t / 3] * h[t % 3];
}
__device__ __forceinline__ float ham5v(int t) {
    const float h[5] = {0.08f, 0.54f, 1.0f, 0.54f, 0.08f};
    return h[t / 5] * h[t % 5];
}

template <int K>
__device__ __forceinline__ void normalize_post(float* m) {
    constexpr int K2 = K * K;
    float mx = -1e30f;
#pragma unroll
    for (int k = 0; k < K2; k++) mx = fmaxf(mx, m[k]);
    float s = 0.f;
#pragma unroll
    for (int k = 0; k < K2; k++) {
        float hv = (K == 3) ? ham3v(k) : ham5v(k);
        float e = __expf(m[k] - mx) * hv;
        m[k] = e;
        s += e;
    }
    float inv = 1.f / s;
#pragma unroll
    for (int k = 0; k < K2; k++) m[k] *= inv;
}

template <int K>
__device__ __forceinline__ void normalize_mask(const float* __restrict src, int stride,
                                               float* m) {
#pragma unroll
    for (int k = 0; k < K * K; k++) m[k] = src[(size_t)k * stride];
    normalize_post<K>(m);
}

struct F4 { float x, y, z, w; };
__device__ __forceinline__ F4 ld4u(const float* p) {
    F4 v;
    __builtin_memcpy(&v, p, 16);
    return v;
}

__device__ __forceinline__ float4 add4(float4 a, float4 b) {
    return make_float4(a.x + b.x, a.y + b.y, a.z + b.z, a.w + b.w);
}

// ---------------- weight prep: transpose to [ci][co] (co contiguous) ----------------
__global__ void prep_w_k(const float* __restrict Whr, const float* __restrict Wlr,
                         const float* __restrict Wenc, const float* __restrict Wenc2,
                         float* __restrict wbase) {
    int tid = blockIdx.x * blockDim.x + threadIdx.x;
    int stride = gridDim.x * blockDim.x;
    float* wt_hr = wbase;
    float* wt_lr = wbase + 16384;
    float* wtE = wbase + 32768;
    float* wtE2 = wbase + 51200;
    for (int i = tid; i < 16384; i += stride) {
        int ci = i >> 6, co = i & 63;
        wt_hr[i] = Whr[co * 256 + ci];
        wt_lr[i] = Wlr[co * 256 + ci];
    }
    for (int i = tid; i < 18432; i += stride) {
        int r = i >> 5, co = i & 31;
        int ci = r / 9, t = r % 9;
        wtE[i] = (co < 25) ? Wenc[(co * 64 + ci) * 9 + t] : 0.f;
    }
    for (int i = tid; i < 9216; i += stride) {
        int r = i >> 4, co = i & 15;
        int ci = r / 9, t = r % 9;
        wtE2[i] = (co < 9) ? Wenc2[(co * 64 + ci) * 9 + t] : 0.f;
    }
}

// ------------- 1x1 conv as LDS-GEMM: 256 thr, 64-px strips, 2 halves -------------
__global__ __launch_bounds__(256) void conv1x1_all_k(
    const float* __restrict hr, const float* __restrict lrf, const float* __restrict wt_hr,
    const float* __restrict wt_lr, const float* __restrict bhr, const float* __restrict blr,
    float* __restrict chf, float* __restrict clf, int N) {
    __shared__ float sm[128 * 64];  // 32 KB
    int b = blockIdx.x;
    const int HRB = (HWH / 64) * N;  // 512
    const float *x, *wt, *bias;
    float* y;
    int HWp, n, px0;
    if (b < HRB) {
        x = hr; wt = wt_hr; bias = bhr; y = chf; HWp = HWH;
        n = b / (HWH / 64);
        px0 = (b % (HWH / 64)) * 64;
    } else {
        int b2 = b - HRB;
        x = lrf; wt = wt_lr; bias = blr; y = clf; HWp = HWL;
        n = b2 / (HWL / 64);
        px0 = (b2 % (HWL / 64)) * 64;
    }
    const float* xb = x + (size_t)n * 256 * HWp + px0;
    int pl = threadIdx.x & 63;
    int co0 = __builtin_amdgcn_readfirstlane((int)(threadIdx.x >> 6)) * 16;  // SGPR
    float acc[16];
#pragma unroll
    for (int j = 0; j < 16; j++) acc[j] = 0.f;
    const float* w0 = wt + co0;  // uniform -> s_load weights
#pragma unroll
    for (int half = 0; half < 2; half++) {
        __syncthreads();
        for (int e = threadIdx.x; e < 2048; e += 256) {
            int ci = e >> 4, q = e & 15;
            *reinterpret_cast<float4*>(sm + ci * 64 + q * 4) =
                *reinterpret_cast<const float4*>(xb + (size_t)(half * 128 + ci) * HWp + q * 4);
        }
        __syncthreads();
        const float* wh = w0 + (half * 128) * 64;
#pragma unroll 8
        for (int ci = 0; ci < 128; ci++) {
            float xv = sm[ci * 64 + pl];
            const float* wr = wh + ci * 64;  // uniform
#pragma unroll
            for (int j = 0; j < 16; j++) acc[j] = fmaf(wr[j], xv, acc[j]);
        }
    }
    float* yb = y + ((size_t)(n * 64 + co0)) * HWp + px0 + pl;
#pragma unroll
    for (int j = 0; j < 16; j++) yb[(size_t)j * HWp] = acc[j] + bias[co0 + j];
}

// ------------- 3x3 conv, 2px/thread, NCI ci per block -------------
template <int COUT, int CH, int PAD, int LOG2W, int HH, int WW, int NCI>
__device__ __forceinline__ void conv3x3_2px(const float* __restrict x,
                                            const float* __restrict wt,
                                            const float* __restrict bias,
                                            float* __restrict y, int n, int g, int pxh,
                                            int ci0, bool addb) {
    constexpr int HWp = HH * WW;
    int px = pxh * 2;
    int yy = px >> LOG2W, xx = px & (WW - 1);
    int co0 = g * CH;  // uniform
    float a0[CH], a1[CH];
#pragma unroll
    for (int j = 0; j < CH; j++) { a0[j] = 0.f; a1[j] = 0.f; }
    const float* xb = x + (size_t)(n * 64 + ci0) * HWp;
    const float* wb0 = wt + (size_t)ci0 * 9 * PAD + co0;
    int roff[3];
    bool rv[3];
#pragma unroll
    for (int r = 0; r < 3; r++) {
        int sy = yy + r - 1;
        rv[r] = (sy >= 0) && (sy < HH);
        roff[r] = sy * WW + xx - 1;
    }
    bool lv = (xx > 0), rgv = (xx < WW - 2);
    for (int ci = 0; ci < NCI; ci++) {
        const float* xc = xb + (size_t)ci * HWp;
        const float* w = wb0 + (size_t)ci * 9 * PAD;
#pragma unroll
        for (int r = 0; r < 3; r++) {
            F4 v = ld4u(xc + roff[r]);  // stays inside d_out; masked below
            float t0 = (rv[r] && lv) ? v.x : 0.f;
            float t1 = rv[r] ? v.y : 0.f;
            float t2 = rv[r] ? v.z : 0.f;
            float t3 = (rv[r] && rgv) ? v.w : 0.f;
#pragma unroll
            for (int j = 0; j < CH; j++) {
                float w0 = w[(r * 3 + 0) * PAD + j];
                float w1 = w[(r * 3 + 1) * PAD + j];
                float w2 = w[(r * 3 + 2) * PAD + j];
                a0[j] = fmaf(w0, t0, fmaf(w1, t1, fmaf(w2, t2, a0[j])));
                a1[j] = fmaf(w0, t1, fmaf(w1, t2, fmaf(w2, t3, a1[j])));
            }
        }
    }
#pragma unroll
    for (int j = 0; j < CH; j++) {
        int co = co0 + j;
        if (co < COUT) {
            float bv = addb ? bias[co] : 0.f;
            float* op = y + ((size_t)(n * COUT + co)) * HWp + px;
            *reinterpret_cast<float2*>(op) = make_float2(a0[j] + bv, a1[j] + bv);
        }
    }
}

// merged: G/K/C, ALL ci-split 8 (NCI=8): 2432 blocks for B=2 (round-20 occupancy lever)
__global__ __launch_bounds__(256) void conv3x3_CGK_k(
    const float* __restrict chf, const float* __restrict clf, const float* __restrict wtE,
    const float* __restrict wtE2, const float* __restrict benc,
    const float* __restrict benc2, float* __restrict mh_P, float* __restrict g_P,
    float* __restrict k_P, int N) {
    const size_t MS = (size_t)N * 9 * HWH, GS = (size_t)N * 25 * HWL,
                 KS = (size_t)N * 9 * HWL;
    const int GBl = 8 * N * 5 * 8, KBl = 8 * N * 2 * 8;
    int b = blockIdx.x;
    if (b < GBl) {
        int pxb = b % 8;
        int n = (b / 8) % N;
        int t = b / (8 * N);
        int g = t % 5, s = t / 5;
        conv3x3_2px<25, 5, 32, 6, WL, WL, 8>(clf, wtE, benc, g_P + s * GS, n, g,
                                             pxb * 256 + (int)threadIdx.x, s * 8, s == 0);
    } else if (b < GBl + KBl) {
        int b2 = b - GBl;
        int pxb = b2 % 8;
        int n = (b2 / 8) % N;
        int t = b2 / (8 * N);
        int g = t % 2, s = t / 2;
        conv3x3_2px<9, 5, 16, 6, WL, WL, 8>(clf, wtE2, benc2, k_P + s * KS, n, g,
                                            pxb * 256 + (int)threadIdx.x, s * 8, s == 0);
    } else {
        int b3 = b - GBl - KBl;
        int pxb = b3 % 32;
        int n = (b3 / 32) % N;
        int t = b3 / (32 * N);
        int g = t % 3, s = t / 3;
        conv3x3_2px<9, 3, 16, 7, WH, WH, 8>(chf, wtE2, benc2, mh_P + s * MS, n, g,
                                            pxb * 256 + (int)threadIdx.x, s * 8, s == 0);
    }
}

// F: chf2 -> m_lrhr partials (co 5x5, ci-split 4)
__global__ __launch_bounds__(256) void conv3x3_F_k(const float* __restrict chf2,
                                                   const float* __restrict wtE,
                                                   const float* __restrict benc,
                                                   float* __restrict mlr_P, int N) {
    const size_t FS = (size_t)N * 25 * HWH;
    int t = blockIdx.x;
    int pxb = t % 32; t /= 32;
    int n = t % N; t /= N;
    int g = t % 5;
    int s = t / 5;
    conv3x3_2px<25, 5, 32, 7, WH, WH, 16>(chf2, wtE, benc, mlr_P + s * FS, n, g,
                                          pxb * 256 + (int)threadIdx.x, s * 16, s == 0);
}

// ---- sum 8 partials: m_hrhr section px-parallel (+ normalized copy); g/k float4 ----
__global__ void sum8n_gkc_k(const float* __restrict mh_P, float* __restrict mh_sum,
                            float* __restrict mh_n, const float4* __restrict g,
                            float4* __restrict g_d, const float4* __restrict k,
                            float4* __restrict k_d, int N) {
    const int NA = N * HWH / 256;
    const int E2 = N * 25 * HWL / 4, E3 = N * 9 * HWL / 4;
    const int NB = E2 / 256;
    const size_t MS = (size_t)N * 9 * HWH;
    int b = blockIdx.x;
    if (b < NA) {
        int lin = b * 256 + threadIdx.x;
        int n = lin / HWH, px = lin % HWH;
        float m[9];
#pragma unroll
        for (int c = 0; c < 9; c++) {
            size_t o = ((size_t)n * 9 + c) * HWH + px;
            float s = 0.f;
#pragma unroll
            for (int p = 0; p < 8; p++) s += mh_P[o + (size_t)p * MS];
            m[c] = s;
            mh_sum[o] = s;
        }
        normalize_post<3>(m);
#pragma unroll
        for (int c = 0; c < 9; c++) mh_n[((size_t)n * 9 + c) * HWH + px] = m[c];
    } else if (b < NA + NB) {
        int i = (b - NA) * 256 + threadIdx.x;
        if (i < E2) {
            float4 s = g[i];
#pragma unroll
            for (int p = 1; p < 8; p++) s = add4(s, g[i + p * E2]);
            g_d[i] = s;
        }
    } else {
        int i = (b - NA - NB) * 256 + threadIdx.x;
        if (i < E3) {
            float4 s = k[i];
#pragma unroll
            for (int p = 1; p < 8; p++) s = add4(s, k[i + p * E3]);
            k_d[i] = s;
        }
    }
}

// ---- sum the 4 F partials (px-parallel, all 25 ch) AND write normalized copy ----
__global__ void sum4fn_k(const float* __restrict p, float* __restrict sum,
                         float* __restrict nrm, int N) {
    int lin = blockIdx.x * 64 + threadIdx.x;  // over N*HWH
    int n = lin / HWH, px = lin % HWH;
    const size_t FS = (size_t)N * 25 * HWH;
    float m[25];
#pragma unroll
    for (int c = 0; c < 25; c++) {
        size_t o = ((size_t)n * 25 + c) * HWH + px;
        float s = p[o] + p[o + FS] + p[o + 2 * FS] + p[o + 3 * FS];
        sum[o] = s;
        m[c] = s;
    }
    normalize_post<5>(m);
    float* np = nrm + (size_t)n * 25 * HWH + px;
#pragma unroll
    for (int c = 0; c < 25; c++) np[(size_t)c * HWH] = m[c];
}

// ---- stage: 4 channel planes into tile[4][18][136], rows y0-1..y0+16, data at col 4+x ----
__device__ __forceinline__ void stage_tile18(const float* __restrict src,
                                             float (*__restrict tile)[18][136], int y0) {
    int tid = threadIdx.x;
    if (tid < 144) {
        int r = tid >> 3, c8 = tid & 7;
        int col = (c8 < 4) ? c8 : 128 + c8;
#pragma unroll
        for (int c = 0; c < 4; c++) tile[c][r][col] = 0.f;
    }
#pragma unroll
    for (int c = 0; c < 4; c++) {
        const float* sp = src + (size_t)c * HWH;
#pragma unroll
        for (int p = 0; p < 3; p++) {
            int e = tid + p * 256;
            if (e < 576) {
                int r = e >> 5, q = e & 31;
                int gy = y0 + r - 1;
                float4 v = make_float4(0.f, 0.f, 0.f, 0.f);
                if (gy >= 0 && gy < WH) v = *(const float4*)(sp + gy * WH + q * 4);
                *(float4*)&tile[c][r][4 + q * 4] = v;
            }
        }
    }
    __syncthreads();
}

// ---- compute: 8 px/thread as TWO SEPARATED QUADS (x0, x0+64); conflict-free b128 ----
template <bool SUBTRACT>
__device__ __forceinline__ void carafe3_tile8(const float (*__restrict tile)[18][136],
                                              const float* __restrict mb, int y0,
                                              float* __restrict ob) {
    int ly = threadIdx.x >> 4;          // 0..15
    int x0 = (threadIdx.x & 15) * 4;    // quad A at x0, quad B at x0+64
    int pxA = (y0 + ly) * WH + x0;
    int pxB = pxA + 64;
    float4 ma[9], mbq[9];
#pragma unroll
    for (int t = 0; t < 9; t++) {
        ma[t] = *(const float4*)(mb + (size_t)t * HWH + pxA);
        mbq[t] = *(const float4*)(mb + (size_t)t * HWH + pxB);
    }
    for (int c = 0; c < 4; c++) {
#pragma unroll
        for (int hf = 0; hf < 2; hf++) {
            int xo = x0 + hf * 64;
            float row[3][6];
#pragma unroll
            for (int r = 0; r < 3; r++) {
                const float* tp = &tile[c][ly + r][0];
                float lft = tp[3 + xo];
                float4 mid = *(const float4*)&tp[4 + xo];  // 16B-stride across lanes
                float rgt = tp[8 + xo];
                row[r][0] = lft; row[r][1] = mid.x; row[r][2] = mid.y; row[r][3] = mid.z;
                row[r][4] = mid.w; row[r][5] = rgt;
            }
            float4 res;
            float* rp = &res.x;
#pragma unroll
            for (int p = 0; p < 4; p++) {
                float s = 0.f;
#pragma unroll
                for (int r = 0; r < 3; r++)
#pragma unroll
                    for (int cc = 0; cc < 3; cc++) {
                        float mv = hf ? ((const float*)&mbq[r * 3 + cc])[p]
                                      : ((const float*)&ma[r * 3 + cc])[p];
                        s = fmaf(mv, row[r][p + cc], s);
                    }
                rp[p] = SUBTRACT ? (2.f * row[1][p + 1] - s) : s;
            }
            *(float4*)(ob + (size_t)c * HWH + (hf ? pxB : pxA)) = res;
        }
    }
}

// ---- hr_out body: one 16-row x 4-ch tile of 2*hr - carafe(hr, m9n) ----
__device__ __forceinline__ void hr_out_body(float* __restrict smem,
                                            const float* __restrict m9n,
                                            const float* __restrict hr,
                                            float* __restrict out1, int b, int N) {
    float(*tile)[18][136] = reinterpret_cast<float(*)[18][136]>(smem);
    int yt = b & 7;
    int g = (b >> 3) & 63;
    int n = b >> 9;
    int y0 = yt * 16;
    int c0 = g * 4;
    stage_tile18(hr + ((size_t)n * 256 + c0) * HWH, tile, y0);
    carafe3_tile8<true>(tile, m9n + (size_t)n * 9 * HWH, y0,
                        out1 + ((size_t)n * 256 + c0) * HWH);
}

// ---- lr_out body: one 16-out-row x 8-ch tile of carafe(lr, out0, up=2) ----
#define LRCHG 8
__device__ __forceinline__ void lr_out_body(float* __restrict smem,
                                            const float* __restrict m_n,
                                            const float* __restrict lrf,
                                            float* __restrict out2, int b, int N) {
    float(*tile)[12][68] = reinterpret_cast<float(*)[12][68]>(smem);
    int yt = b & 7;
    int g = (b >> 3) & 31;
    int n = b >> 8;
    int y0 = yt * 16;
    int hbase = y0 >> 1;
    int c0 = g * LRCHG;
    const float* lrb = lrf + ((size_t)n * 256 + c0) * HWL;
    if (threadIdx.x < 48) {
        int r = threadIdx.x >> 2, c4 = threadIdx.x & 3;
        int col = (c4 < 2) ? c4 : 64 + c4;
#pragma unroll
        for (int c = 0; c < LRCHG; c++) tile[c][r][col] = 0.f;
    }
#pragma unroll
    for (int c = 0; c < LRCHG; c++) {
        const float* sp = lrb + (size_t)c * HWL;
#pragma unroll
        for (int p = 0; p < 2; p++) {
            int e = threadIdx.x + p * 256;
            if (e < 384) {
                int r = e >> 5, q = e & 31;
                int h = hbase + r - 2;
                float2 v = make_float2(0.f, 0.f);
                if (h >= 0 && h < WL) v = *(const float2*)(sp + h * WL + q * 2);
                *(float2*)&tile[c][r][2 + q * 2] = v;
            }
        }
    }
    __syncthreads();
    const float* mb = m_n + (size_t)n * 25 * HWH;
    float* ob = out2 + ((size_t)n * 256 + c0) * HWH;
#pragma unroll
    for (int i = 0; i < 2; i++) {
        int q = threadIdx.x + 256 * i;
        int qy = q >> 6, qx = q & 63;
        int Y0 = y0 + 2 * qy;
        int X0 = 2 * qx;
        float2 mk0[25], mk1[25];
#pragma unroll
        for (int k = 0; k < 25; k++) {
            mk0[k] = *(const float2*)(mb + (size_t)k * HWH + Y0 * WH + X0);
            mk1[k] = *(const float2*)(mb + (size_t)k * HWH + (Y0 + 1) * WH + X0);
        }
        for (int c = 0; c < LRCHG; c++) {
            float a00 = 0.f, a01 = 0.f, a10 = 0.f, a11 = 0.f;
#pragma unroll
            for (int k = 0; k < 25; k++) {
                float v = tile[c][qy + k / 5][qx + k % 5];
                a00 = fmaf(mk0[k].x, v, a00);
                a01 = fmaf(mk0[k].y, v, a01);
                a10 = fmaf(mk1[k].x, v, a10);
                a11 = fmaf(mk1[k].y, v, a11);
            }
            float* op = ob + (size_t)c * HWH + (size_t)Y0 * WH + X0;
            *(float2*)op = make_float2(a00, a01);
            *(float2*)(op + WH) = make_float2(a10, a11);
        }
    }
}

// ------- stage D+E: chf2 = 2*chf - carafe(chf, m_hrhr_n, k=3, up=1); 16-row tiles -------
__global__ __launch_bounds__(256) void fuse_de_k(const float* __restrict chf,
                                                 const float* __restrict m9n,
                                                 float* __restrict chf2, int N) {
    __shared__ float tile[4][18][136];  // 39168 B
    int b = blockIdx.x;
    int yt = b & 7;
    int g = (b >> 3) & 15;
    int n = b >> 7;
    int y0 = yt * 16;
    int c0 = g * 4;
    stage_tile18(chf + ((size_t)n * 64 + c0) * HWH, tile, y0);
    carafe3_tile8<true>(tile, m9n + (size_t)n * 9 * HWH, y0,
                        chf2 + ((size_t)n * 64 + c0) * HWH);
}

// ---- stage H+I: mask_lr = m_lrhr_sum + carafe(g_sum, m_lrhr_n, k=5, up=2); 5 co-groups ----
__global__ void fuse_hi_k(const float* __restrict msum, const float* __restrict mn,
                          const float* __restrict g, float* __restrict mask_lr, int N) {
    int b = blockIdx.x;
    int pxb = b % 64;
    int n = (b / 64) % N;
    int co0 = (b / (64 * N)) * 5;
    int px = pxb * 256 + threadIdx.x;
    int Y = px >> 7, X = px & 127;
    int h = Y >> 1, w = X >> 1;
    const float* mb = msum + (size_t)n * 25 * HWH + px;
    const float* nb = mn + (size_t)n * 25 * HWH + px;
    float ml[25];
#pragma unroll
    for (int k = 0; k < 25; k++) ml[k] = nb[(size_t)k * HWH];  // pre-normalized
    float acc[5];
#pragma unroll
    for (int j = 0; j < 5; j++) acc[j] = 0.f;
    const float* gb = g + ((size_t)n * 25 + co0) * HWL;
    for (int k = 0; k < 25; k++) {
        int sy = h + k / 5 - 2, sx = w + k % 5 - 2;
        if (sy >= 0 && sy < WL && sx >= 0 && sx < WL) {
            int off = sy * WL + sx;
            float mk = ml[k];
#pragma unroll
            for (int j = 0; j < 5; j++)
                acc[j] = fmaf(mk, gb[(size_t)j * HWL + off], acc[j]);
        }
    }
#pragma unroll
    for (int j = 0; j < 5; j++)
        mask_lr[((size_t)(n * 25 + co0 + j)) * HWH + px] =
            mb[(size_t)(co0 + j) * HWH] + acc[j];
}

// ---- J+L+norm merged: out0 = normalize(mask_lr); mask_hr_n = normalize(m_hrhr_sum +
//      carafe(k_sum, out0, k=5, up=2)) ----
__global__ void fuse_l_norm_k(const float* __restrict mask_lr, const float* __restrict kf,
                              const float* __restrict mh_sum, float* __restrict out0,
                              float* __restrict mask_hr_n, int N) {
    int b = blockIdx.x;
    int px = (b % 256) * 64 + threadIdx.x;
    int n = b / 256;
    int Y = px >> 7, X = px & 127;
    int h = Y >> 1, w = X >> 1;
    float ml[25];
    normalize_mask<5>(mask_lr + (size_t)n * 25 * HWH + px, HWH, ml);
    float* op = out0 + (size_t)n * 25 * HWH + px;
#pragma unroll
    for (int k = 0; k < 25; k++) op[(size_t)k * HWH] = ml[k];
    float acc[9];
#pragma unroll
    for (int j = 0; j < 9; j++) acc[j] = 0.f;
    const float* kb = kf + (size_t)n * 9 * HWL;
    for (int k = 0; k < 25; k++) {
        int sy = h + k / 5 - 2, sx = w + k % 5 - 2;
        if (sy >= 0 && sy < WL && sx >= 0 && sx < WL) {
            int off = sy * WL + sx;
            float mk = ml[k];
#pragma unroll
            for (int j = 0; j < 9; j++)
                acc[j] = fmaf(mk, kb[(size_t)j * HWL + off], acc[j]);
        }
    }
    float mh[9];
#pragma unroll
    for (int j = 0; j < 9; j++)
        mh[j] = mh_sum[((size_t)(n * 9 + j)) * HWH + px] + acc[j];
    normalize_post<3>(mh);
    float* dp = mask_hr_n + (size_t)n * 9 * HWH + px;
#pragma unroll
    for (int j = 0; j < 9; j++) dp[(size_t)j * HWH] = mh[j];
}

// ---- standalone hr_out / lr_out (fallback path when ws too small) ----
__global__ __launch_bounds__(256) void hr_out_k(const float* __restrict m9n,
                                                const float* __restrict hr,
                                                float* __restrict out1, int N) {
    __shared__ float smem[4 * 18 * 136];
    hr_out_body(smem, m9n, hr, out1, blockIdx.x, N);
}

__global__ __launch_bounds__(256) void lr_out_k(const float* __restrict m_n,
                                                const float* __restrict lrf,
                                                float* __restrict out2, int N) {
    __shared__ float smem[LRCHG * 12 * 68];
    lr_out_body(smem, m_n, lrf, out2, blockIdx.x, N);
}

// ---- merged final dispatch (ws path): hr blocks first (1024), lr blocks backfill (512) ----
__global__ __launch_bounds__(256) void hrlr_out_k(const float* __restrict m9n,
                                                  const float* __restrict hr,
                                                  float* __restrict out1,
                                                  const float* __restrict m_n,
                                                  const float* __restrict lrf,
                                                  float* __restrict out2, int N) {
    __shared__ float smem[4 * 18 * 136];  // 39168 B (union; lr needs 26112 B)
    int b = blockIdx.x;
    const int HRB = N * 512;
    if (b < HRB) {
        hr_out_body(smem, m9n, hr, out1, b, N);
    } else {
        lr_out_body(smem, m_n, lrf, out2, b - HRB, N);
    }
}

extern "C" void kernel_launch(void* const* d_in, const int* in_sizes, int n_in, void* d_out,
                              int out_size, void* d_ws, size_t ws_size, hipStream_t stream) {
    const float* hr = (const float*)d_in[0];
    const float* lr = (const float*)d_in[1];
    const float* Whr = (const float*)d_in[2];
    const float* bhr = (const float*)d_in[3];
    const float* Wlr = (const float*)d_in[4];
    const float* blr = (const float*)d_in[5];
    const float* Wenc = (const float*)d_in[6];
    const float* benc = (const float*)d_in[7];
    const float* Wenc2 = (const float*)d_in[8];
    const float* benc2 = (const float*)d_in[9];
    float* out = (float*)d_out;
    const int B = in_sizes[0] / (256 * HWH);  // 2

    float* out0 = out;                           // B*25*HWH  (final: mask_lr_n)
    float* O1 = out + (size_t)B * 25 * HWH;      // B*256*HWH (final: hr_out)
    float* O2 = O1 + (size_t)B * 256 * HWH;      // B*256*HWH (final: lr_out)

    const size_t MS = (size_t)B * 9 * HWH;   // 294912
    const size_t GS = (size_t)B * 25 * HWL;  // 204800
    const size_t KS = (size_t)B * 9 * HWL;   // 73728
    const size_t FS = (size_t)B * 25 * HWH;  // 819200

    // --- scratch inside O2 (all consumed before O2 is overwritten); ends ~7.15M < 8.39M ---
    float* wbase = O2;                                // 60416 floats of weights
    float* wt_hr = wbase;
    float* wt_lr = wbase + 16384;
    float* wtE = wbase + 32768;
    float* wtE2 = wbase + 51200;
    float* mh_P = O2 + 60416;                         // 8 partials x MS
    float* g_P = mh_P + 8 * MS;                       // 8 x GS
    float* k_P = g_P + 8 * GS;                        // 8 x KS
    float* m_hrhr_sum = k_P + 8 * KS;                 // MS
    float* g_sum = m_hrhr_sum + MS;                   // GS
    float* k_sum = g_sum + GS;                        // KS
    float* m_lrhr_sum = k_sum + KS;                   // FS
    float* mask_hr_n_o2 = m_lrhr_sum + FS;            // MS (fallback home)
    float* m_lrhr_n = mask_hr_n_o2 + MS;              // FS (ends 7,154,688)

    // --- scratch inside O1 (consumed before hr_out overwrites O1); total 8,290,304 ---
    float* chf = O1;                                  // B*64*HWH = 2097152
    float* chf2 = chf + (size_t)B * 64 * HWH;         // 2097152
    float* clf = chf2 + (size_t)B * 64 * HWH;         // B*64*HWL = 524288
    float* mlr_P = clf + (size_t)B * 64 * HWL;        // 4 partials x FS = 3276800
    float* m_hrhr_n = mlr_P + 4 * FS;                 // MS (ends 8,290,304)
    float* mask_lr = mlr_P;                           // alias: partials dead after sum4fn

    // mask_hr_n home: d_ws if it fits (enables merged final dispatch), else O2 scratch.
    const bool use_ws = ws_size >= MS * sizeof(float);
    float* mask_hr_n = use_ws ? (float*)d_ws : mask_hr_n_o2;

    prep_w_k<<<64, 256, 0, stream>>>(Whr, Wlr, Wenc, Wenc2, wbase);
    // A+B: 1x1 convs as LDS-GEMM (640 blocks)
    conv1x1_all_k<<<(HWH / 64) * B + (HWL / 64) * B, 256, 0, stream>>>(
        hr, lr, wt_hr, wt_lr, bhr, blr, chf, clf, B);
    // G + K + C merged, 2px/thread, ci-split 8 (2432 blocks for B=2)
    conv3x3_CGK_k<<<8 * B * 5 * 8 + 8 * B * 2 * 8 + 32 * B * 3 * 8, 256, 0, stream>>>(
        chf, clf, wtE, wtE2, benc, benc2, mh_P, g_P, k_P, B);
    // sum 8 partials; m_hrhr section also writes normalized copy
    {
        int NA = B * HWH / 256;
        int NB = (B * 25 * HWL / 4) / 256, NC = (B * 9 * HWL / 4) / 256;
        sum8n_gkc_k<<<NA + NB + NC, 256, 0, stream>>>(
            mh_P, m_hrhr_sum, m_hrhr_n, (const float4*)g_P, (float4*)g_sum,
            (const float4*)k_P, (float4*)k_sum, B);
    }
    // D+E: chf2 (16-row tiles, dual-quad 8px/thread, conflict-free LDS)
    fuse_de_k<<<B * 128, 256, 0, stream>>>(chf, m_hrhr_n, chf2, B);
    // F: chf2 -> m_lrhr partials, 2px/thread, ci-split 4 (1280 blocks)
    conv3x3_F_k<<<32 * B * 5 * 4, 256, 0, stream>>>(chf2, wtE, benc, mlr_P, B);
    // sum F partials px-parallel -> m_lrhr_sum + m_lrhr_n (normalized once)
    sum4fn_k<<<B * HWH / 64, 64, 0, stream>>>(mlr_P, m_lrhr_sum, m_lrhr_n, B);
    // H+I: mask_lr (5 co-groups; reads pre-normalized masks)
    fuse_hi_k<<<64 * B * 5, 256, 0, stream>>>(m_lrhr_sum, m_lrhr_n, g_sum, mask_lr, B);
    // J+L+norm merged: out0 + mask_hr_n in one dispatch
    fuse_l_norm_k<<<256 * B, 64, 0, stream>>>(mask_lr, k_sum, m_hrhr_sum, out0, mask_hr_n,
                                              B);
    if (use_ws) {
        // merged final dispatch: hr_out (1024 blocks) + lr_out (512 blocks) overlap
        hrlr_out_k<<<B * 512 + B * 256, 256, 0, stream>>>(mask_hr_n, hr, O1, out0, lr, O2,
                                                          B);
    } else {
        hr_out_k<<<B * 512, 256, 0, stream>>>(mask_hr_n, hr, O1, B);
        lr_out_k<<<B * 256, 256, 0, stream>>>(out0, lr, O2, B);
    }
}

// Round 22
// 145.942 us; speedup vs baseline: 1.0828x; 1.0828x over previous
//
#include <hip/hip_runtime.h>

// FreqFusion forward, f32. Shapes fixed: B=2, C=256, CC=64, HR=128x128, LR=64x64.
// Round-21: revert to round-20 best configuration (149.8 us). CGK ci-split 4 (NCI=16).
#define HWH 16384   // 128*128
#define HWL 4096    // 64*64
#define WH 128
#define WL 64

// ---------------- hamming helpers ----------------
__device__ __forceinline__ float ham3v(int t) {
    const float h[3] = {0.08f, 1.0f, 0.08f};
    return h[t / 3] * h[t % 3];
}
__device__ __forceinline__ float ham5v(int t) {
    const float h[5] = {0.08f, 0.54f, 1.0f, 0.54f, 0.08f};
    return h[t / 5] * h[t % 5];
}

template <int K>
__device__ __forceinline__ void normalize_post(float* m) {
    constexpr int K2 = K * K;
    float mx = -1e30f;
#pragma unroll
    for (int k = 0; k < K2; k++) mx = fmaxf(mx, m[k]);
    float s = 0.f;
#pragma unroll
    for (int k = 0; k < K2; k++) {
        float hv = (K == 3) ? ham3v(k) : ham5v(k);
        float e = __expf(m[k] - mx) * hv;
        m[k] = e;
        s += e;
    }
    float inv = 1.f / s;
#pragma unroll
    for (int k = 0; k < K2; k++) m[k] *= inv;
}

template <int K>
__device__ __forceinline__ void normalize_mask(const float* __restrict src, int stride,
                                               float* m) {
#pragma unroll
    for (int k = 0; k < K * K; k++) m[k] = src[(size_t)k * stride];
    normalize_post<K>(m);
}

struct F4 { float x, y, z, w; };
__device__ __forceinline__ F4 ld4u(const float* p) {
    F4 v;
    __builtin_memcpy(&v, p, 16);
    return v;
}

__device__ __forceinline__ float4 add4(float4 a, float4 b) {
    return make_float4(a.x + b.x, a.y + b.y, a.z + b.z, a.w + b.w);
}

// ---------------- weight prep: transpose to [ci][co] (co contiguous) ----------------
__global__ void prep_w_k(const float* __restrict Whr, const float* __restrict Wlr,
                         const float* __restrict Wenc, const float* __restrict Wenc2,
                         float* __restrict wbase) {
    int tid = blockIdx.x * blockDim.x + threadIdx.x;
    int stride = gridDim.x * blockDim.x;
    float* wt_hr = wbase;
    float* wt_lr = wbase + 16384;
    float* wtE = wbase + 32768;
    float* wtE2 = wbase + 51200;
    for (int i = tid; i < 16384; i += stride) {
        int ci = i >> 6, co = i & 63;
        wt_hr[i] = Whr[co * 256 + ci];
        wt_lr[i] = Wlr[co * 256 + ci];
    }
    for (int i = tid; i < 18432; i += stride) {
        int r = i >> 5, co = i & 31;
        int ci = r / 9, t = r % 9;
        wtE[i] = (co < 25) ? Wenc[(co * 64 + ci) * 9 + t] : 0.f;
    }
    for (int i = tid; i < 9216; i += stride) {
        int r = i >> 4, co = i & 15;
        int ci = r / 9, t = r % 9;
        wtE2[i] = (co < 9) ? Wenc2[(co * 64 + ci) * 9 + t] : 0.f;
    }
}

// ------------- 1x1 conv as LDS-GEMM: 256 thr, 64-px strips, 2 halves -------------
__global__ __launch_bounds__(256) void conv1x1_all_k(
    const float* __restrict hr, const float* __restrict lrf, const float* __restrict wt_hr,
    const float* __restrict wt_lr, const float* __restrict bhr, const float* __restrict blr,
    float* __restrict chf, float* __restrict clf, int N) {
    __shared__ float sm[128 * 64];  // 32 KB
    int b = blockIdx.x;
    const int HRB = (HWH / 64) * N;  // 512
    const float *x, *wt, *bias;
    float* y;
    int HWp, n, px0;
    if (b < HRB) {
        x = hr; wt = wt_hr; bias = bhr; y = chf; HWp = HWH;
        n = b / (HWH / 64);
        px0 = (b % (HWH / 64)) * 64;
    } else {
        int b2 = b - HRB;
        x = lrf; wt = wt_lr; bias = blr; y = clf; HWp = HWL;
        n = b2 / (HWL / 64);
        px0 = (b2 % (HWL / 64)) * 64;
    }
    const float* xb = x + (size_t)n * 256 * HWp + px0;
    int pl = threadIdx.x & 63;
    int co0 = __builtin_amdgcn_readfirstlane((int)(threadIdx.x >> 6)) * 16;  // SGPR
    float acc[16];
#pragma unroll
    for (int j = 0; j < 16; j++) acc[j] = 0.f;
    const float* w0 = wt + co0;  // uniform -> s_load weights
#pragma unroll
    for (int half = 0; half < 2; half++) {
        __syncthreads();
        for (int e = threadIdx.x; e < 2048; e += 256) {
            int ci = e >> 4, q = e & 15;
            *reinterpret_cast<float4*>(sm + ci * 64 + q * 4) =
                *reinterpret_cast<const float4*>(xb + (size_t)(half * 128 + ci) * HWp + q * 4);
        }
        __syncthreads();
        const float* wh = w0 + (half * 128) * 64;
#pragma unroll 8
        for (int ci = 0; ci < 128; ci++) {
            float xv = sm[ci * 64 + pl];
            const float* wr = wh + ci * 64;  // uniform
#pragma unroll
            for (int j = 0; j < 16; j++) acc[j] = fmaf(wr[j], xv, acc[j]);
        }
    }
    float* yb = y + ((size_t)(n * 64 + co0)) * HWp + px0 + pl;
#pragma unroll
    for (int j = 0; j < 16; j++) yb[(size_t)j * HWp] = acc[j] + bias[co0 + j];
}

// ------------- 3x3 conv, 2px/thread, NCI ci per block -------------
template <int COUT, int CH, int PAD, int LOG2W, int HH, int WW, int NCI>
__device__ __forceinline__ void conv3x3_2px(const float* __restrict x,
                                            const float* __restrict wt,
                                            const float* __restrict bias,
                                            float* __restrict y, int n, int g, int pxh,
                                            int ci0, bool addb) {
    constexpr int HWp = HH * WW;
    int px = pxh * 2;
    int yy = px >> LOG2W, xx = px & (WW - 1);
    int co0 = g * CH;  // uniform
    float a0[CH], a1[CH];
#pragma unroll
    for (int j = 0; j < CH; j++) { a0[j] = 0.f; a1[j] = 0.f; }
    const float* xb = x + (size_t)(n * 64 + ci0) * HWp;
    const float* wb0 = wt + (size_t)ci0 * 9 * PAD + co0;
    int roff[3];
    bool rv[3];
#pragma unroll
    for (int r = 0; r < 3; r++) {
        int sy = yy + r - 1;
        rv[r] = (sy >= 0) && (sy < HH);
        roff[r] = sy * WW + xx - 1;
    }
    bool lv = (xx > 0), rgv = (xx < WW - 2);
    for (int ci = 0; ci < NCI; ci++) {
        const float* xc = xb + (size_t)ci * HWp;
        const float* w = wb0 + (size_t)ci * 9 * PAD;
#pragma unroll
        for (int r = 0; r < 3; r++) {
            F4 v = ld4u(xc + roff[r]);  // stays inside d_out; masked below
            float t0 = (rv[r] && lv) ? v.x : 0.f;
            float t1 = rv[r] ? v.y : 0.f;
            float t2 = rv[r] ? v.z : 0.f;
            float t3 = (rv[r] && rgv) ? v.w : 0.f;
#pragma unroll
            for (int j = 0; j < CH; j++) {
                float w0 = w[(r * 3 + 0) * PAD + j];
                float w1 = w[(r * 3 + 1) * PAD + j];
                float w2 = w[(r * 3 + 2) * PAD + j];
                a0[j] = fmaf(w0, t0, fmaf(w1, t1, fmaf(w2, t2, a0[j])));
                a1[j] = fmaf(w0, t1, fmaf(w1, t2, fmaf(w2, t3, a1[j])));
            }
        }
    }
#pragma unroll
    for (int j = 0; j < CH; j++) {
        int co = co0 + j;
        if (co < COUT) {
            float bv = addb ? bias[co] : 0.f;
            float* op = y + ((size_t)(n * COUT + co)) * HWp + px;
            *reinterpret_cast<float2*>(op) = make_float2(a0[j] + bv, a1[j] + bv);
        }
    }
}

// merged: G (clf->g partials), K (clf->k partials), C (chf->m_hrhr partials); all ci-split 4
__global__ __launch_bounds__(256) void conv3x3_CGK_k(
    const float* __restrict chf, const float* __restrict clf, const float* __restrict wtE,
    const float* __restrict wtE2, const float* __restrict benc,
    const float* __restrict benc2, float* __restrict mh_P, float* __restrict g_P,
    float* __restrict k_P, int N) {
    const size_t MS = (size_t)N * 9 * HWH, GS = (size_t)N * 25 * HWL,
                 KS = (size_t)N * 9 * HWL;
    const int GBl = 8 * N * 5 * 4, KBl = 8 * N * 2 * 4;
    int b = blockIdx.x;
    if (b < GBl) {
        int pxb = b % 8;
        int n = (b / 8) % N;
        int t = b / (8 * N);
        int g = t % 5, s = t / 5;
        conv3x3_2px<25, 5, 32, 6, WL, WL, 16>(clf, wtE, benc, g_P + s * GS, n, g,
                                              pxb * 256 + (int)threadIdx.x, s * 16, s == 0);
    } else if (b < GBl + KBl) {
        int b2 = b - GBl;
        int pxb = b2 % 8;
        int n = (b2 / 8) % N;
        int t = b2 / (8 * N);
        int g = t % 2, s = t / 2;
        conv3x3_2px<9, 5, 16, 6, WL, WL, 16>(clf, wtE2, benc2, k_P + s * KS, n, g,
                                             pxb * 256 + (int)threadIdx.x, s * 16, s == 0);
    } else {
        int b3 = b - GBl - KBl;
        int pxb = b3 % 32;
        int n = (b3 / 32) % N;
        int t = b3 / (32 * N);
        int g = t % 3, s = t / 3;
        conv3x3_2px<9, 3, 16, 7, WH, WH, 16>(chf, wtE2, benc2, mh_P + s * MS, n, g,
                                             pxb * 256 + (int)threadIdx.x, s * 16, s == 0);
    }
}

// F: chf2 -> m_lrhr partials (co 5x5, ci-split 4)
__global__ __launch_bounds__(256) void conv3x3_F_k(const float* __restrict chf2,
                                                   const float* __restrict wtE,
                                                   const float* __restrict benc,
                                                   float* __restrict mlr_P, int N) {
    const size_t FS = (size_t)N * 25 * HWH;
    int t = blockIdx.x;
    int pxb = t % 32; t /= 32;
    int n = t % N; t /= N;
    int g = t % 5;
    int s = t / 5;
    conv3x3_2px<25, 5, 32, 7, WH, WH, 16>(chf2, wtE, benc, mlr_P + s * FS, n, g,
                                          pxb * 256 + (int)threadIdx.x, s * 16, s == 0);
}

// ---- sum partials: m_hrhr section px-parallel, also writes normalized copy; g/k float4 ----
__global__ void sum4n_gkc_k(const float* __restrict mh_P, float* __restrict mh_sum,
                            float* __restrict mh_n, const float4* __restrict g,
                            float4* __restrict g_d, const float4* __restrict k,
                            float4* __restrict k_d, int N) {
    const int NA = N * HWH / 256;
    const int E2 = N * 25 * HWL / 4, E3 = N * 9 * HWL / 4;
    const int NB = E2 / 256;
    const size_t MS = (size_t)N * 9 * HWH;
    int b = blockIdx.x;
    if (b < NA) {
        int lin = b * 256 + threadIdx.x;
        int n = lin / HWH, px = lin % HWH;
        float m[9];
#pragma unroll
        for (int c = 0; c < 9; c++) {
            size_t o = ((size_t)n * 9 + c) * HWH + px;
            float s = mh_P[o] + mh_P[o + MS] + mh_P[o + 2 * MS] + mh_P[o + 3 * MS];
            m[c] = s;
            mh_sum[o] = s;
        }
        normalize_post<3>(m);
#pragma unroll
        for (int c = 0; c < 9; c++) mh_n[((size_t)n * 9 + c) * HWH + px] = m[c];
    } else if (b < NA + NB) {
        int i = (b - NA) * 256 + threadIdx.x;
        if (i < E2) g_d[i] = add4(add4(g[i], g[i + E2]), add4(g[i + 2 * E2], g[i + 3 * E2]));
    } else {
        int i = (b - NA - NB) * 256 + threadIdx.x;
        if (i < E3) k_d[i] = add4(add4(k[i], k[i + E3]), add4(k[i + 2 * E3], k[i + 3 * E3]));
    }
}

// ---- sum the 4 F partials (px-parallel, all 25 ch) AND write normalized copy ----
__global__ void sum4fn_k(const float* __restrict p, float* __restrict sum,
                         float* __restrict nrm, int N) {
    int lin = blockIdx.x * 64 + threadIdx.x;  // over N*HWH
    int n = lin / HWH, px = lin % HWH;
    const size_t FS = (size_t)N * 25 * HWH;
    float m[25];
#pragma unroll
    for (int c = 0; c < 25; c++) {
        size_t o = ((size_t)n * 25 + c) * HWH + px;
        float s = p[o] + p[o + FS] + p[o + 2 * FS] + p[o + 3 * FS];
        sum[o] = s;
        m[c] = s;
    }
    normalize_post<5>(m);
    float* np = nrm + (size_t)n * 25 * HWH + px;
#pragma unroll
    for (int c = 0; c < 25; c++) np[(size_t)c * HWH] = m[c];
}

// ---- stage: 4 channel planes into tile[4][18][136], rows y0-1..y0+16, data at col 4+x ----
__device__ __forceinline__ void stage_tile18(const float* __restrict src,
                                             float (*__restrict tile)[18][136], int y0) {
    int tid = threadIdx.x;
    if (tid < 144) {
        int r = tid >> 3, c8 = tid & 7;
        int col = (c8 < 4) ? c8 : 128 + c8;
#pragma unroll
        for (int c = 0; c < 4; c++) tile[c][r][col] = 0.f;
    }
#pragma unroll
    for (int c = 0; c < 4; c++) {
        const float* sp = src + (size_t)c * HWH;
#pragma unroll
        for (int p = 0; p < 3; p++) {
            int e = tid + p * 256;
            if (e < 576) {
                int r = e >> 5, q = e & 31;
                int gy = y0 + r - 1;
                float4 v = make_float4(0.f, 0.f, 0.f, 0.f);
                if (gy >= 0 && gy < WH) v = *(const float4*)(sp + gy * WH + q * 4);
                *(float4*)&tile[c][r][4 + q * 4] = v;
            }
        }
    }
    __syncthreads();
}

// ---- compute: 8 px/thread as TWO SEPARATED QUADS (x0, x0+64); conflict-free b128 ----
template <bool SUBTRACT>
__device__ __forceinline__ void carafe3_tile8(const float (*__restrict tile)[18][136],
                                              const float* __restrict mb, int y0,
                                              float* __restrict ob) {
    int ly = threadIdx.x >> 4;          // 0..15
    int x0 = (threadIdx.x & 15) * 4;    // quad A at x0, quad B at x0+64
    int pxA = (y0 + ly) * WH + x0;
    int pxB = pxA + 64;
    float4 ma[9], mbq[9];
#pragma unroll
    for (int t = 0; t < 9; t++) {
        ma[t] = *(const float4*)(mb + (size_t)t * HWH + pxA);
        mbq[t] = *(const float4*)(mb + (size_t)t * HWH + pxB);
    }
    for (int c = 0; c < 4; c++) {
#pragma unroll
        for (int hf = 0; hf < 2; hf++) {
            int xo = x0 + hf * 64;
            float row[3][6];
#pragma unroll
            for (int r = 0; r < 3; r++) {
                const float* tp = &tile[c][ly + r][0];
                float lft = tp[3 + xo];
                float4 mid = *(const float4*)&tp[4 + xo];  // 16B-stride across lanes
                float rgt = tp[8 + xo];
                row[r][0] = lft; row[r][1] = mid.x; row[r][2] = mid.y; row[r][3] = mid.z;
                row[r][4] = mid.w; row[r][5] = rgt;
            }
            float4 res;
            float* rp = &res.x;
#pragma unroll
            for (int p = 0; p < 4; p++) {
                float s = 0.f;
#pragma unroll
                for (int r = 0; r < 3; r++)
#pragma unroll
                    for (int cc = 0; cc < 3; cc++) {
                        float mv = hf ? ((const float*)&mbq[r * 3 + cc])[p]
                                      : ((const float*)&ma[r * 3 + cc])[p];
                        s = fmaf(mv, row[r][p + cc], s);
                    }
                rp[p] = SUBTRACT ? (2.f * row[1][p + 1] - s) : s;
            }
            *(float4*)(ob + (size_t)c * HWH + (hf ? pxB : pxA)) = res;
        }
    }
}

// ---- hr_out body: one 16-row x 4-ch tile of 2*hr - carafe(hr, m9n) ----
__device__ __forceinline__ void hr_out_body(float* __restrict smem,
                                            const float* __restrict m9n,
                                            const float* __restrict hr,
                                            float* __restrict out1, int b, int N) {
    float(*tile)[18][136] = reinterpret_cast<float(*)[18][136]>(smem);
    int yt = b & 7;
    int g = (b >> 3) & 63;
    int n = b >> 9;
    int y0 = yt * 16;
    int c0 = g * 4;
    stage_tile18(hr + ((size_t)n * 256 + c0) * HWH, tile, y0);
    carafe3_tile8<true>(tile, m9n + (size_t)n * 9 * HWH, y0,
                        out1 + ((size_t)n * 256 + c0) * HWH);
}

// ---- lr_out body: one 16-out-row x 8-ch tile of carafe(lr, out0, up=2) ----
#define LRCHG 8
__device__ __forceinline__ void lr_out_body(float* __restrict smem,
                                            const float* __restrict m_n,
                                            const float* __restrict lrf,
                                            float* __restrict out2, int b, int N) {
    float(*tile)[12][68] = reinterpret_cast<float(*)[12][68]>(smem);
    int yt = b & 7;
    int g = (b >> 3) & 31;
    int n = b >> 8;
    int y0 = yt * 16;
    int hbase = y0 >> 1;
    int c0 = g * LRCHG;
    const float* lrb = lrf + ((size_t)n * 256 + c0) * HWL;
    if (threadIdx.x < 48) {
        int r = threadIdx.x >> 2, c4 = threadIdx.x & 3;
        int col = (c4 < 2) ? c4 : 64 + c4;
#pragma unroll
        for (int c = 0; c < LRCHG; c++) tile[c][r][col] = 0.f;
    }
#pragma unroll
    for (int c = 0; c < LRCHG; c++) {
        const float* sp = lrb + (size_t)c * HWL;
#pragma unroll
        for (int p = 0; p < 2; p++) {
            int e = threadIdx.x + p * 256;
            if (e < 384) {
                int r = e >> 5, q = e & 31;
                int h = hbase + r - 2;
                float2 v = make_float2(0.f, 0.f);
                if (h >= 0 && h < WL) v = *(const float2*)(sp + h * WL + q * 2);
                *(float2*)&tile[c][r][2 + q * 2] = v;
            }
        }
    }
    __syncthreads();
    const float* mb = m_n + (size_t)n * 25 * HWH;
    float* ob = out2 + ((size_t)n * 256 + c0) * HWH;
#pragma unroll
    for (int i = 0; i < 2; i++) {
        int q = threadIdx.x + 256 * i;
        int qy = q >> 6, qx = q & 63;
        int Y0 = y0 + 2 * qy;
        int X0 = 2 * qx;
        float2 mk0[25], mk1[25];
#pragma unroll
        for (int k = 0; k < 25; k++) {
            mk0[k] = *(const float2*)(mb + (size_t)k * HWH + Y0 * WH + X0);
            mk1[k] = *(const float2*)(mb + (size_t)k * HWH + (Y0 + 1) * WH + X0);
        }
        for (int c = 0; c < LRCHG; c++) {
            float a00 = 0.f, a01 = 0.f, a10 = 0.f, a11 = 0.f;
#pragma unroll
            for (int k = 0; k < 25; k++) {
                float v = tile[c][qy + k / 5][qx + k % 5];
                a00 = fmaf(mk0[k].x, v, a00);
                a01 = fmaf(mk0[k].y, v, a01);
                a10 = fmaf(mk1[k].x, v, a10);
                a11 = fmaf(mk1[k].y, v, a11);
            }
            float* op = ob + (size_t)c * HWH + (size_t)Y0 * WH + X0;
            *(float2*)op = make_float2(a00, a01);
            *(float2*)(op + WH) = make_float2(a10, a11);
        }
    }
}

// ------- stage D+E: chf2 = 2*chf - carafe(chf, m_hrhr_n, k=3, up=1); 16-row tiles -------
__global__ __launch_bounds__(256) void fuse_de_k(const float* __restrict chf,
                                                 const float* __restrict m9n,
                                                 float* __restrict chf2, int N) {
    __shared__ float tile[4][18][136];  // 39168 B
    int b = blockIdx.x;
    int yt = b & 7;
    int g = (b >> 3) & 15;
    int n = b >> 7;
    int y0 = yt * 16;
    int c0 = g * 4;
    stage_tile18(chf + ((size_t)n * 64 + c0) * HWH, tile, y0);
    carafe3_tile8<true>(tile, m9n + (size_t)n * 9 * HWH, y0,
                        chf2 + ((size_t)n * 64 + c0) * HWH);
}

// ---- stage H+I: mask_lr = m_lrhr_sum + carafe(g_sum, m_lrhr_n, k=5, up=2); 5 co-groups ----
__global__ void fuse_hi_k(const float* __restrict msum, const float* __restrict mn,
                          const float* __restrict g, float* __restrict mask_lr, int N) {
    int b = blockIdx.x;
    int pxb = b % 64;
    int n = (b / 64) % N;
    int co0 = (b / (64 * N)) * 5;
    int px = pxb * 256 + threadIdx.x;
    int Y = px >> 7, X = px & 127;
    int h = Y >> 1, w = X >> 1;
    const float* mb = msum + (size_t)n * 25 * HWH + px;
    const float* nb = mn + (size_t)n * 25 * HWH + px;
    float ml[25];
#pragma unroll
    for (int k = 0; k < 25; k++) ml[k] = nb[(size_t)k * HWH];  // pre-normalized
    float acc[5];
#pragma unroll
    for (int j = 0; j < 5; j++) acc[j] = 0.f;
    const float* gb = g + ((size_t)n * 25 + co0) * HWL;
    for (int k = 0; k < 25; k++) {
        int sy = h + k / 5 - 2, sx = w + k % 5 - 2;
        if (sy >= 0 && sy < WL && sx >= 0 && sx < WL) {
            int off = sy * WL + sx;
            float mk = ml[k];
#pragma unroll
            for (int j = 0; j < 5; j++)
                acc[j] = fmaf(mk, gb[(size_t)j * HWL + off], acc[j]);
        }
    }
#pragma unroll
    for (int j = 0; j < 5; j++)
        mask_lr[((size_t)(n * 25 + co0 + j)) * HWH + px] =
            mb[(size_t)(co0 + j) * HWH] + acc[j];
}

// ---- J+L+norm merged: out0 = normalize(mask_lr); mask_hr_n = normalize(m_hrhr_sum +
//      carafe(k_sum, out0, k=5, up=2)) ----
__global__ void fuse_l_norm_k(const float* __restrict mask_lr, const float* __restrict kf,
                              const float* __restrict mh_sum, float* __restrict out0,
                              float* __restrict mask_hr_n, int N) {
    int b = blockIdx.x;
    int px = (b % 256) * 64 + threadIdx.x;
    int n = b / 256;
    int Y = px >> 7, X = px & 127;
    int h = Y >> 1, w = X >> 1;
    float ml[25];
    normalize_mask<5>(mask_lr + (size_t)n * 25 * HWH + px, HWH, ml);
    float* op = out0 + (size_t)n * 25 * HWH + px;
#pragma unroll
    for (int k = 0; k < 25; k++) op[(size_t)k * HWH] = ml[k];
    float acc[9];
#pragma unroll
    for (int j = 0; j < 9; j++) acc[j] = 0.f;
    const float* kb = kf + (size_t)n * 9 * HWL;
    for (int k = 0; k < 25; k++) {
        int sy = h + k / 5 - 2, sx = w + k % 5 - 2;
        if (sy >= 0 && sy < WL && sx >= 0 && sx < WL) {
            int off = sy * WL + sx;
            float mk = ml[k];
#pragma unroll
            for (int j = 0; j < 9; j++)
                acc[j] = fmaf(mk, kb[(size_t)j * HWL + off], acc[j]);
        }
    }
    float mh[9];
#pragma unroll
    for (int j = 0; j < 9; j++)
        mh[j] = mh_sum[((size_t)(n * 9 + j)) * HWH + px] + acc[j];
    normalize_post<3>(mh);
    float* dp = mask_hr_n + (size_t)n * 9 * HWH + px;
#pragma unroll
    for (int j = 0; j < 9; j++) dp[(size_t)j * HWH] = mh[j];
}

// ---- standalone hr_out / lr_out (fallback path when ws too small) ----
__global__ __launch_bounds__(256) void hr_out_k(const float* __restrict m9n,
                                                const float* __restrict hr,
                                                float* __restrict out1, int N) {
    __shared__ float smem[4 * 18 * 136];
    hr_out_body(smem, m9n, hr, out1, blockIdx.x, N);
}

__global__ __launch_bounds__(256) void lr_out_k(const float* __restrict m_n,
                                                const float* __restrict lrf,
                                                float* __restrict out2, int N) {
    __shared__ float smem[LRCHG * 12 * 68];
    lr_out_body(smem, m_n, lrf, out2, blockIdx.x, N);
}

// ---- merged final dispatch (ws path): hr blocks first (1024), lr blocks backfill (512) ----
__global__ __launch_bounds__(256) void hrlr_out_k(const float* __restrict m9n,
                                                  const float* __restrict hr,
                                                  float* __restrict out1,
                                                  const float* __restrict m_n,
                                                  const float* __restrict lrf,
                                                  float* __restrict out2, int N) {
    __shared__ float smem[4 * 18 * 136];  // 39168 B (union; lr needs 26112 B)
    int b = blockIdx.x;
    const int HRB = N * 512;
    if (b < HRB) {
        hr_out_body(smem, m9n, hr, out1, b, N);
    } else {
        lr_out_body(smem, m_n, lrf, out2, b - HRB, N);
    }
}

extern "C" void kernel_launch(void* const* d_in, const int* in_sizes, int n_in, void* d_out,
                              int out_size, void* d_ws, size_t ws_size, hipStream_t stream) {
    const float* hr = (const float*)d_in[0];
    const float* lr = (const float*)d_in[1];
    const float* Whr = (const float*)d_in[2];
    const float* bhr = (const float*)d_in[3];
    const float* Wlr = (const float*)d_in[4];
    const float* blr = (const float*)d_in[5];
    const float* Wenc = (const float*)d_in[6];
    const float* benc = (const float*)d_in[7];
    const float* Wenc2 = (const float*)d_in[8];
    const float* benc2 = (const float*)d_in[9];
    float* out = (float*)d_out;
    const int B = in_sizes[0] / (256 * HWH);  // 2

    float* out0 = out;                           // B*25*HWH  (final: mask_lr_n)
    float* O1 = out + (size_t)B * 25 * HWH;      // B*256*HWH (final: hr_out)
    float* O2 = O1 + (size_t)B * 256 * HWH;      // B*256*HWH (final: lr_out)

    const size_t MS = (size_t)B * 9 * HWH;   // 294912
    const size_t GS = (size_t)B * 25 * HWL;  // 204800
    const size_t KS = (size_t)B * 9 * HWL;   // 73728
    const size_t FS = (size_t)B * 25 * HWH;  // 819200

    // --- scratch inside O2 (all consumed before O2 is overwritten); ends ~4.86M ---
    float* wbase = O2;                                // 60416 floats of weights
    float* wt_hr = wbase;
    float* wt_lr = wbase + 16384;
    float* wtE = wbase + 32768;
    float* wtE2 = wbase + 51200;
    float* mh_P = O2 + 60416;                         // 4 partials x MS
    float* g_P = mh_P + 4 * MS;                       // 4 x GS
    float* k_P = g_P + 4 * GS;                        // 4 x KS
    float* m_hrhr_sum = k_P + 4 * KS;                 // MS
    float* g_sum = m_hrhr_sum + MS;                   // GS
    float* k_sum = g_sum + GS;                        // KS
    float* m_lrhr_sum = k_sum + KS;                   // FS
    float* mask_hr_n_o2 = m_lrhr_sum + FS;            // MS (fallback home)
    float* m_lrhr_n = mask_hr_n_o2 + MS;              // FS (ends 4,860,928)

    // --- scratch inside O1 (consumed before hr_out overwrites O1); total 8,290,304 ---
    float* chf = O1;                                  // B*64*HWH = 2097152
    float* chf2 = chf + (size_t)B * 64 * HWH;         // 2097152
    float* clf = chf2 + (size_t)B * 64 * HWH;         // B*64*HWL = 524288
    float* mlr_P = clf + (size_t)B * 64 * HWL;        // 4 partials x FS = 3276800
    float* m_hrhr_n = mlr_P + 4 * FS;                 // MS (ends 8,290,304)
    float* mask_lr = mlr_P;                           // alias: partials dead after sum4fn

    // mask_hr_n home: d_ws if it fits (enables merged final dispatch), else O2 scratch.
    const bool use_ws = ws_size >= MS * sizeof(float);
    float* mask_hr_n = use_ws ? (float*)d_ws : mask_hr_n_o2;

    prep_w_k<<<64, 256, 0, stream>>>(Whr, Wlr, Wenc, Wenc2, wbase);
    // A+B: 1x1 convs as LDS-GEMM (640 blocks)
    conv1x1_all_k<<<(HWH / 64) * B + (HWL / 64) * B, 256, 0, stream>>>(
        hr, lr, wt_hr, wt_lr, bhr, blr, chf, clf, B);
    // G + K + C merged, 2px/thread, ci-split 4 (1216 blocks for B=2)
    conv3x3_CGK_k<<<8 * B * 5 * 4 + 8 * B * 2 * 4 + 32 * B * 3 * 4, 256, 0, stream>>>(
        chf, clf, wtE, wtE2, benc, benc2, mh_P, g_P, k_P, B);
    // sum partials; m_hrhr section also writes normalized copy
    {
        int NA = B * HWH / 256;
        int NB = (B * 25 * HWL / 4) / 256, NC = (B * 9 * HWL / 4) / 256;
        sum4n_gkc_k<<<NA + NB + NC, 256, 0, stream>>>(
            mh_P, m_hrhr_sum, m_hrhr_n, (const float4*)g_P, (float4*)g_sum,
            (const float4*)k_P, (float4*)k_sum, B);
    }
    // D+E: chf2 (16-row tiles, dual-quad 8px/thread, conflict-free LDS)
    fuse_de_k<<<B * 128, 256, 0, stream>>>(chf, m_hrhr_n, chf2, B);
    // F: chf2 -> m_lrhr partials, 2px/thread, ci-split 4 (1280 blocks)
    conv3x3_F_k<<<32 * B * 5 * 4, 256, 0, stream>>>(chf2, wtE, benc, mlr_P, B);
    // sum F partials px-parallel -> m_lrhr_sum + m_lrhr_n (normalized once)
    sum4fn_k<<<B * HWH / 64, 64, 0, stream>>>(mlr_P, m_lrhr_sum, m_lrhr_n, B);
    // H+I: mask_lr (5 co-groups; reads pre-normalized masks)
    fuse_hi_k<<<64 * B * 5, 256, 0, stream>>>(m_lrhr_sum, m_lrhr_n, g_sum, mask_lr, B);
    // J+L+norm merged: out0 + mask_hr_n in one dispatch
    fuse_l_norm_k<<<256 * B, 64, 0, stream>>>(mask_lr, k_sum, m_hrhr_sum, out0, mask_hr_n,
                                              B);
    if (use_ws) {
        // merged final dispatch: hr_out (1024 blocks) + lr_out (512 blocks) overlap
        hrlr_out_k<<<B * 512 + B * 256, 256, 0, stream>>>(mask_hr_n, hr, O1, out0, lr, O2,
                                                          B);
    } else {
        hr_out_k<<<B * 512, 256, 0, stream>>>(mask_hr_n, hr, O1, B);
        lr_out_k<<<B * 256, 256, 0, stream>>>(out0, lr, O2, B);
    }
}